// Round 5
// baseline (110.756 us; speedup 1.0000x reference)
//
#include <hip/hip_runtime.h>
#include <hip/hip_cooperative_groups.h>

namespace cg = cooperative_groups;

#define E 128
#define Fb 32
#define TSH 136    // u16 stride per LDS table row (272 B)
#define ROWB 272   // table row byte stride
#define NBLK 768   // 6 tiles x 128 batches; 3 blocks/CU co-resident

__device__ inline float bf2f(unsigned short u) {
    union { unsigned int i; float f; } x;
    x.i = ((unsigned int)u) << 16;
    return x.f;
}

// ---- unit bodies (shared between fused kernel and fallback kernels) --------

// T[a,c] = sum_u 1/((|u-a|+1)(|u-c|+1)) - S(a)S(c)/(E-1), bf16 RNE
__device__ inline void table_unit(int a, int c, unsigned short* __restrict__ table) {
    float sa = 0.f, sc = 0.f, g = 0.f;
    for (int u = 0; u < E; ++u) {
        float wa = 1.0f / (float)(abs(u - a) + 1);
        float wc = 1.0f / (float)(abs(u - c) + 1);
        sa += wa;
        sc += wc;
        g += wa * wc;
    }
    float t = g - sa * sc * (1.0f / (float)(E - 1));
    union { float f; unsigned int i; } x;
    x.f = t;
    unsigned int r = (x.i + 0x7FFFu + ((x.i >> 16) & 1u)) >> 16;
    table[a * E + c] = (unsigned short)r;
}

// stable rank count for electrode e at column (b,f); xs holds the 128 values
__device__ inline void rank_count(const float* __restrict__ xs, float v, int e,
                                  int bf, int b, int f,
                                  unsigned char* __restrict__ ranks,
                                  unsigned char* __restrict__ ranksT) {
    int cnt = 0;
    const float4* x4 = (const float4*)xs;
#pragma unroll 8
    for (int j4 = 0; j4 < E / 4; ++j4) {
        float4 q = x4[j4];
        int j = j4 * 4;
        cnt += (int)(q.x < v) + (int)((q.x == v) & (j + 0 < e));
        cnt += (int)(q.y < v) + (int)((q.y == v) & (j + 1 < e));
        cnt += (int)(q.z < v) + (int)((q.z == v) & (j + 2 < e));
        cnt += (int)(q.w < v) + (int)((q.w == v) & (j + 3 < e));
    }
    ranks[bf * E + e] = (unsigned char)cnt;
    ranksT[(b * E + e) * Fb + f] = (unsigned char)cnt;
}

// round-4 acc body: out[b, tile t] = mean_f T[rj, rk] with symmetry mirrors
__device__ inline void acc_body(int b, int t, int tid,
                                const unsigned char* __restrict__ ranks,
                                const unsigned char* __restrict__ ranksT,
                                const unsigned short* __restrict__ table,
                                float* __restrict__ out,
                                unsigned short* __restrict__ tbl,
                                float* __restrict__ trans) {
    const int ti  = (t < 4) ? (t >> 1) : (t - 2);   // {0,0,1,1,2,3}
    const int cb  = (t < 4) ? (t & 1) : 1;          // {0,1,0,1,1,1}
    const int mir = (t < 4) ? (t & 1) : 0;          // {0,1,0,1,0,0}
    const int j0 = ti * 32, k0 = cb * 64;

    const int wave = tid >> 6, lane = tid & 63;
    const int k = k0 + lane;
    const unsigned char* rb  = ranks  + b * (Fb * E);
    const unsigned char* rbT = ranksT + b * (Fb * E);

    int rk2[Fb];
#pragma unroll
    for (int f4 = 0; f4 < 8; ++f4) {
        uchar4 qv = *(const uchar4*)&rbT[k * Fb + f4 * 4];
        rk2[f4 * 4 + 0] = (int)qv.x * 2;
        rk2[f4 * 4 + 1] = (int)qv.y * 2;
        rk2[f4 * 4 + 2] = (int)qv.z * 2;
        rk2[f4 * 4 + 3] = (int)qv.w * 2;
    }

    int rj272[4];
#pragma unroll
    for (int rp = 0; rp < 4; ++rp) {
        int fl = rp * 8 + (lane >> 3);
        int row = j0 + wave + 4 * (lane & 7);
        rj272[rp] = (int)rb[fl * E + row] * ROWB;
    }

    const uint4* t16 = (const uint4*)table;
#pragma unroll
    for (int i = 0; i < 8; ++i) {
        int idx = tid + i * 256;
        uint4 v = t16[idx];
        int a = idx >> 4;
        int c = (idx & 15) * 8;
        *(uint4*)&tbl[a * TSH + c] = v;
    }
    __syncthreads();

    float acc[8] = {0.f, 0.f, 0.f, 0.f, 0.f, 0.f, 0.f, 0.f};
#pragma unroll
    for (int f = 0; f < Fb; ++f) {
        const int rg = f >> 3, li = (f & 7) << 3;
        const int ck = rk2[f];
#pragma unroll
        for (int g = 0; g < 8; ++g) {
            int ro = __builtin_amdgcn_readlane(rj272[rg], li | g);
            acc[g] += bf2f(*(const unsigned short*)((const char*)tbl + ro + ck));
        }
    }

    const float s = 1.0f / (float)Fb;
    float* ob = out + b * (E * E);
#pragma unroll
    for (int g = 0; g < 8; ++g)
        ob[(j0 + wave + 4 * g) * E + k] = acc[g] * s;

    if (mir) {
#pragma unroll
        for (int g = 0; g < 8; ++g)
            trans[lane * 33 + (wave + 4 * g)] = acc[g] * s;
        __syncthreads();
#pragma unroll
        for (int g = 0; g < 8; ++g) {
            int rr = (tid >> 5) + 8 * g;
            int cc = tid & 31;
            ob[(k0 + rr) * E + (j0 + cc)] = trans[rr * 33 + cc];
        }
    }
}

// ---------------- fused cooperative kernel ----------------------------------
// Phase 1: 4224 units (128 table rows + 4096 rank columns) spread over
// 768 blocks x 2 half-blocks x 3 rounds. Phase 2 (after grid sync): acc.
__global__ __launch_bounds__(256, 3) void spearman_fused(
        const float* __restrict__ de,
        unsigned char* __restrict__ ranks,
        unsigned char* __restrict__ ranksT,
        unsigned short* __restrict__ table,
        float* __restrict__ out) {
    __shared__ __align__(16) unsigned short tbl[E * TSH];  // 34816 B
    __shared__ __align__(16) float trans[64 * 33];         // 8448 B
    float* xs = trans;                                     // phase-1 alias

    const int tid = threadIdx.x;
    const int half = tid >> 7;       // which 128-thread half-unit
    const int th = tid & 127;

    // ---- phase 1 ----
#pragma unroll
    for (int r = 0; r < 3; ++r) {
        const int u = (int)blockIdx.x * 2 + half + r * (NBLK * 2);
        const bool valid = u < 128 + 128 * Fb;
        const bool is_rank = valid && (u >= 128);
        int bf = u - 128, b = bf >> 5, f = bf & 31;
        float v = 0.f;
        if (is_rank) {
            v = de[(b * E + th) * Fb + f];
            xs[half * 128 + th] = v;
        }
        __syncthreads();
        if (is_rank) {
            rank_count(&xs[half * 128], v, th, bf, b, f, ranks, ranksT);
        } else if (valid) {
            table_unit(u, th, table);
        }
        __syncthreads();
    }

    cg::this_grid().sync();

    // ---- phase 2 ----
    acc_body((int)blockIdx.x / 6, (int)blockIdx.x % 6, tid,
             ranks, ranksT, table, out, tbl, trans);
}

// ---------------- fallback path (round-4 two-kernel version) ----------------
__global__ void spearman_prep(const float* __restrict__ de,
                              unsigned char* __restrict__ ranks,
                              unsigned char* __restrict__ ranksT,
                              unsigned short* __restrict__ table) {
    if (blockIdx.x < E) {
        table_unit(blockIdx.x, threadIdx.x, table);
        return;
    }
    int bf = blockIdx.x - E;
    int b = bf >> 5, f = bf & 31;
    __shared__ __align__(16) float xs[E];
    int e = threadIdx.x;
    float v = de[(b * E + e) * Fb + f];
    xs[e] = v;
    __syncthreads();
    rank_count(xs, v, e, bf, b, f, ranks, ranksT);
}

__global__ __launch_bounds__(256, 3) void spearman_acc(
        const unsigned char* __restrict__ ranks,
        const unsigned char* __restrict__ ranksT,
        const unsigned short* __restrict__ table,
        float* __restrict__ out) {
    __shared__ __align__(16) unsigned short tbl[E * TSH];
    __shared__ __align__(16) float trans[64 * 33];
    acc_body((int)blockIdx.x / 6, (int)blockIdx.x % 6, (int)threadIdx.x,
             ranks, ranksT, table, out, tbl, trans);
}

extern "C" void kernel_launch(void* const* d_in, const int* in_sizes, int n_in,
                              void* d_out, int out_size, void* d_ws, size_t ws_size,
                              hipStream_t stream) {
    const float* de = (const float*)d_in[0];     // [128,128,32] f32
    float* out = (float*)d_out;                  // [128,128,128] f32

    const int B = 128;
    unsigned char* ranks  = (unsigned char*)d_ws;                          // 512KB
    unsigned char* ranksT = (unsigned char*)d_ws + (size_t)B * Fb * E;     // 512KB
    unsigned short* table = (unsigned short*)((char*)d_ws + 2 * (size_t)B * Fb * E);  // 32KB

    void* params[5] = { (void*)&de, (void*)&ranks, (void*)&ranksT,
                        (void*)&table, (void*)&out };
    hipError_t e = hipLaunchCooperativeKernel((const void*)spearman_fused,
                                              dim3(NBLK), dim3(256),
                                              params, 0, stream);
    if (e != hipSuccess) {
        (void)hipGetLastError();
        spearman_prep<<<E + B * Fb, E, 0, stream>>>(de, ranks, ranksT, table);
        spearman_acc<<<B * 6, 256, 0, stream>>>(ranks, ranksT, table, out);
    }
}

// Round 6
// 28.041 us; speedup vs baseline: 3.9498x; 3.9498x over previous
//
#include <hip/hip_runtime.h>

#define E 128
#define Fb 32
#define TSH 136    // u16 stride per LDS table row (272 B)
#define ROWB 272   // table row byte stride

__device__ inline float bf2f(unsigned short u) {
    union { unsigned int i; float f; } x;
    x.i = ((unsigned int)u) << 16;
    return x.f;
}

// monotone bijection f32 -> u32 (ascending), finite values, no NaN expected
__device__ inline unsigned int sortable(float f) {
    union { float f; unsigned int u; } x;
    x.f = f;
    unsigned int u = x.u;
    return (u & 0x80000000u) ? ~u : (u | 0x80000000u);
}

// ---------------- Kernel 1: table (blocks 0..63) + ranks (blocks 64..319) ---
// table: T[a,c] = sum_u rcp(|u-a|)*rcp(|u-c|) - S(a)S(c)/127, bf16 RNE.
// ranks: stable rank along electrodes == #{j: key_j < key_e} with
//        key = (sortable(x)<<7)|index  (exact argsort(argsort) semantics).
__global__ __launch_bounds__(256) void spearman_prep(
        const float* __restrict__ de,
        unsigned char* __restrict__ ranks,
        unsigned char* __restrict__ ranksT,
        unsigned short* __restrict__ table) {
    const int tid = threadIdx.x;

    if (blockIdx.x < 64) {
        // ---- table blocks: 256 entries each (2 rows of T) ----
        __shared__ float rcp[E];
        if (tid < E) rcp[tid] = 1.0f / (float)(tid + 1);
        __syncthreads();
        int idx = (int)blockIdx.x * 256 + tid;
        int a = idx >> 7, c = idx & 127;
        float sa = 0.f, sc = 0.f, g = 0.f;
#pragma unroll 16
        for (int u = 0; u < E; ++u) {
            float wa = rcp[abs(u - a)];
            float wc = rcp[abs(u - c)];
            sa += wa;
            sc += wc;
            g += wa * wc;
        }
        float t = g - sa * sc * (1.0f / (float)(E - 1));
        union { float f; unsigned int i; } x;
        x.f = t;
        unsigned int r = (x.i + 0x7FFFu + ((x.i >> 16) & 1u)) >> 16;  // RNE bf16
        table[idx] = (unsigned short)r;
        return;
    }

    // ---- rank blocks: one (batch b, freq-half fh) slab of 128e x 16f ----
    __shared__ __align__(16) unsigned long long keyT[16][130];  // 16.6 KB
    __shared__ __align__(16) unsigned char rt[16][128];         // 2 KB
    const int bid = (int)blockIdx.x - 64;
    const int b = bid >> 1, fh = bid & 1;

    {
        const int e = tid & 127, q = tid >> 7;   // q in {0,1}
#pragma unroll
        for (int p = 0; p < 2; ++p) {
            const int f4 = q * 2 + p;            // float4 group 0..3 within 16 f
            float4 v = *(const float4*)(de + ((size_t)(b * E + e)) * Fb + fh * 16 + f4 * 4);
            keyT[f4 * 4 + 0][e] = ((unsigned long long)sortable(v.x) << 7) | (unsigned)e;
            keyT[f4 * 4 + 1][e] = ((unsigned long long)sortable(v.y) << 7) | (unsigned)e;
            keyT[f4 * 4 + 2][e] = ((unsigned long long)sortable(v.z) << 7) | (unsigned)e;
            keyT[f4 * 4 + 3][e] = ((unsigned long long)sortable(v.w) << 7) | (unsigned)e;
        }
    }
    __syncthreads();

    // all-pairs count: wave w owns f in [w*4, w*4+4); lanes = e and e+64
    const int wv = tid >> 6, lane = tid & 63;
#pragma unroll
    for (int fi = 0; fi < 4; ++fi) {
        const int f = wv * 4 + fi;
        const unsigned long long k0 = keyT[f][lane];
        const unsigned long long k1 = keyT[f][lane + 64];
        int c0 = 0, c1 = 0;
#pragma unroll 8
        for (int j = 0; j < E; j += 2) {
            unsigned long long ka = keyT[f][j];
            unsigned long long kb = keyT[f][j + 1];
            c0 += (int)(ka < k0) + (int)(kb < k0);
            c1 += (int)(ka < k1) + (int)(kb < k1);
        }
        rt[f][lane] = (unsigned char)c0;
        rt[f][lane + 64] = (unsigned char)c1;
    }
    __syncthreads();

    // coalesced dumps of both layouts
    if (tid < 128) {
        // ranks[(b*32 + fh*16 + f)*128 + e] : 16B per thread
        const int f = tid >> 3, e0 = (tid & 7) * 16;
        *(uint4*)(ranks + ((size_t)b * Fb + fh * 16 + f) * E + e0) = *(const uint4*)&rt[f][e0];
        // ranksT[(b*128+e)*32 + fh*16 + f] : pack 16 bytes of column e
        const int e = tid;
        unsigned int w[4];
#pragma unroll
        for (int g = 0; g < 4; ++g) {
            w[g] = (unsigned)rt[g * 4 + 0][e]
                 | ((unsigned)rt[g * 4 + 1][e] << 8)
                 | ((unsigned)rt[g * 4 + 2][e] << 16)
                 | ((unsigned)rt[g * 4 + 3][e] << 24);
        }
        *(uint4*)(ranksT + ((size_t)b * E + e) * Fb + fh * 16) =
            make_uint4(w[0], w[1], w[2], w[3]);
    }
}

// ---------------- Kernel 2: out[b,j,k] = mean_f T[rj, rk], symmetric -------
// (round-4 body, unchanged: 6 tiles of 32x64 per batch + transpose mirrors)
__global__ __launch_bounds__(256, 3) void spearman_acc(
        const unsigned char* __restrict__ ranks,
        const unsigned char* __restrict__ ranksT,
        const unsigned short* __restrict__ table,
        float* __restrict__ out) {
    __shared__ __align__(16) unsigned short tbl[E * TSH];  // 34816 B
    __shared__ __align__(16) float trans[64 * 33];         // 8448 B
    const int tid = threadIdx.x;
    const int b = blockIdx.x / 6;
    const int t = blockIdx.x % 6;
    const int ti  = (t < 4) ? (t >> 1) : (t - 2);   // {0,0,1,1,2,3}
    const int cb  = (t < 4) ? (t & 1) : 1;          // {0,1,0,1,1,1}
    const int mir = (t < 4) ? (t & 1) : 0;          // {0,1,0,1,0,0}
    const int j0 = ti * 32, k0 = cb * 64;

    const int wave = tid >> 6, lane = tid & 63;
    const int k = k0 + lane;
    const unsigned char* rb  = ranks  + b * (Fb * E);
    const unsigned char* rbT = ranksT + b * (Fb * E);

    int rk2[Fb];
#pragma unroll
    for (int f4 = 0; f4 < 8; ++f4) {
        uchar4 qv = *(const uchar4*)&rbT[k * Fb + f4 * 4];
        rk2[f4 * 4 + 0] = (int)qv.x * 2;
        rk2[f4 * 4 + 1] = (int)qv.y * 2;
        rk2[f4 * 4 + 2] = (int)qv.z * 2;
        rk2[f4 * 4 + 3] = (int)qv.w * 2;
    }

    int rj272[4];
#pragma unroll
    for (int rp = 0; rp < 4; ++rp) {
        int fl = rp * 8 + (lane >> 3);
        int row = j0 + wave + 4 * (lane & 7);
        rj272[rp] = (int)rb[fl * E + row] * ROWB;
    }

    const uint4* t16 = (const uint4*)table;
#pragma unroll
    for (int i = 0; i < 8; ++i) {
        int idx = tid + i * 256;
        uint4 v = t16[idx];
        int a = idx >> 4;
        int c = (idx & 15) * 8;
        *(uint4*)&tbl[a * TSH + c] = v;
    }
    __syncthreads();

    float acc[8] = {0.f, 0.f, 0.f, 0.f, 0.f, 0.f, 0.f, 0.f};
#pragma unroll
    for (int f = 0; f < Fb; ++f) {
        const int rg = f >> 3, li = (f & 7) << 3;
        const int ck = rk2[f];
#pragma unroll
        for (int g = 0; g < 8; ++g) {
            int ro = __builtin_amdgcn_readlane(rj272[rg], li | g);
            acc[g] += bf2f(*(const unsigned short*)((const char*)tbl + ro + ck));
        }
    }

    const float s = 1.0f / (float)Fb;
    float* ob = out + b * (E * E);
#pragma unroll
    for (int g = 0; g < 8; ++g)
        ob[(j0 + wave + 4 * g) * E + k] = acc[g] * s;

    if (mir) {
#pragma unroll
        for (int g = 0; g < 8; ++g)
            trans[lane * 33 + (wave + 4 * g)] = acc[g] * s;
        __syncthreads();
#pragma unroll
        for (int g = 0; g < 8; ++g) {
            int rr = (tid >> 5) + 8 * g;
            int cc = tid & 31;
            ob[(k0 + rr) * E + (j0 + cc)] = trans[rr * 33 + cc];
        }
    }
}

extern "C" void kernel_launch(void* const* d_in, const int* in_sizes, int n_in,
                              void* d_out, int out_size, void* d_ws, size_t ws_size,
                              hipStream_t stream) {
    const float* de = (const float*)d_in[0];     // [128,128,32] f32
    float* out = (float*)d_out;                  // [128,128,128] f32

    const int B = 128;
    unsigned char* ranks  = (unsigned char*)d_ws;                          // 512KB
    unsigned char* ranksT = (unsigned char*)d_ws + (size_t)B * Fb * E;     // 512KB
    unsigned short* table = (unsigned short*)((char*)d_ws + 2 * (size_t)B * Fb * E);  // 32KB

    spearman_prep<<<64 + B * 2, 256, 0, stream>>>(de, ranks, ranksT, table);
    spearman_acc<<<B * 6, 256, 0, stream>>>(ranks, ranksT, table, out);
}